// Round 11
// baseline (449.553 us; speedup 1.0000x reference)
//
#include <hip/hip_runtime.h>
#include <hip/hip_fp16.h>

#define N_NODES 50000
#define N_EDGES 600000
#define NBLK 49  // ceil(50000/1024)

typedef unsigned int u32;

__device__ __forceinline__ float2 h2f2(u32 u) {
    __half2 h = *(__half2*)&u;
    return __half22float2(h);
}

// ---------------- adj layout detection (int64 vs int32) ----------------
__global__ void k_detect(const int* __restrict__ adj_w, int* __restrict__ mode) {
    if (threadIdx.x == 0 && blockIdx.x == 0) {
        int allz = 1;
        for (int i = 1; i < 128; i += 2)
            if (adj_w[i] != 0) { allz = 0; break; }
        *mode = allz;  // 1 => int64 layout
    }
}
__device__ __forceinline__ int adj_to(const int* a, int m, int e) {
    return m ? a[4 * e + 2] : a[2 * e + 1];
}
__device__ __forceinline__ int adj_fro(const int* a, int m, int e) {
    return m ? a[4 * e] : a[2 * e];
}

// ---------------- CSR build ----------------
__global__ void k_count(const int* __restrict__ adj_w, const int* __restrict__ mode,
                        int* __restrict__ deg) {
    int e = blockIdx.x * blockDim.x + threadIdx.x;
    if (e < N_EDGES) atomicAdd(&deg[adj_to(adj_w, *mode, e)], 1);
}

__global__ void k_scan1(const int* __restrict__ deg, int* __restrict__ row_ptr,
                        int* __restrict__ bsum) {
    __shared__ int s[1024];
    int tid = threadIdx.x, i = blockIdx.x * 1024 + tid;
    int v = (i < N_NODES) ? deg[i] : 0;
    s[tid] = v;
    __syncthreads();
    for (int off = 1; off < 1024; off <<= 1) {
        int t = (tid >= off) ? s[tid - off] : 0;
        __syncthreads();
        s[tid] += t;
        __syncthreads();
    }
    if (i < N_NODES) row_ptr[i] = s[tid] - v;
    if (tid == 1023) bsum[blockIdx.x] = s[1023];
}

__global__ void k_scan2(int* __restrict__ bsum) {
    __shared__ int s[64];
    int tid = threadIdx.x;
    int v = (tid < NBLK) ? bsum[tid] : 0;
    s[tid] = v;
    __syncthreads();
    for (int off = 1; off < 64; off <<= 1) {
        int t = (tid >= off) ? s[tid - off] : 0;
        __syncthreads();
        s[tid] += t;
        __syncthreads();
    }
    if (tid < NBLK) bsum[tid] = s[tid] - v;
}

__global__ void k_scan3(const int* __restrict__ deg, int* __restrict__ row_ptr,
                        const int* __restrict__ bsum, int* __restrict__ cursor,
                        float* __restrict__ inv_deg) {
    int i = blockIdx.x * 1024 + threadIdx.x;
    if (i < N_NODES) {
        int rp = row_ptr[i] + bsum[i >> 10];
        row_ptr[i] = rp;
        cursor[i] = rp;
        inv_deg[i] = 1.0f / fmaxf((float)deg[i], 1.0f);
    }
    if (i == 0) row_ptr[N_NODES] = N_EDGES;
}

__global__ void k_fill(const int* __restrict__ adj_w, const int* __restrict__ mode,
                       int* __restrict__ cursor, int* __restrict__ edge_src) {
    int e = blockIdx.x * blockDim.x + threadIdx.x;
    if (e < N_EDGES) {
        int m = *mode;
        int to = adj_to(adj_w, m, e);
        int slot = atomicAdd(&cursor[to], 1);
        edge_src[slot] = adj_fro(adj_w, m, e);
    }
}

// ---- dense GEMM, 4-way K-split, wr[32] truly resident, f16 output ----
// grid 12500: cg = bx&1 (64-col group), ch = bx>>1 (8-row chunk).
// thread: q = l>>4 (K quarter), c = cg*64 + w*16 + (l&15).
template <typename IT, bool RELU>
__global__ __launch_bounds__(256, 4) void k_dense(const IT* __restrict__ in,
                                                  _Float16* __restrict__ outp,
                                                  const float* __restrict__ W,
                                                  const float* __restrict__ bias) {
    __shared__ __align__(16) float xs[8][128];
    const int t = threadIdx.x, w = t >> 6, l = t & 63;
    const int q = l >> 4, c = (blockIdx.x & 1) * 64 + w * 16 + (l & 15);
    const int R0 = (blockIdx.x >> 1) * 8;
    float wr[32];
#pragma unroll
    for (int j = 0; j < 32; j++) wr[j] = W[(32 * q + j) * 128 + c];
    const float b = bias[c];
    if constexpr (sizeof(IT) == 4) {
        ((float4*)xs)[t] = ((const float4*)(in + (size_t)R0 * 128))[t];
    } else {
        uint2 u = ((const uint2*)(in + (size_t)R0 * 128))[t];
        float2 lo = h2f2(u.x), hi = h2f2(u.y);
        ((float4*)xs)[t] = make_float4(lo.x, lo.y, hi.x, hi.y);
    }
    __syncthreads();
#pragma unroll
    for (int r = 0; r < 8; r++) {
        float a = 0.f;
#pragma unroll
        for (int jj = 0; jj < 8; jj++) {
            float4 x4 = *(const float4*)&xs[r][32 * q + jj * 4];
            a += x4.x * wr[jj * 4] + x4.y * wr[jj * 4 + 1] +
                 x4.z * wr[jj * 4 + 2] + x4.w * wr[jj * 4 + 3];
        }
        a += __shfl_xor(a, 16);
        a += __shfl_xor(a, 32);
        if (l < 16) {
            float v = a + b;
            if (RELU) v = fmaxf(v, 0.f);
            outp[(size_t)(R0 + r) * 128 + c] = (_Float16)v;
        }
    }
}

// ---- fused gather + dense: hio = relu(hio + msg @ W); h stored f16 ----
// split-2 wr[64]; launch_bounds(256,3) -> VGPR cap 170, W honestly resident.
__global__ __launch_bounds__(256, 3) void k_msggemm(const _Float16* __restrict__ hin,
                                                    _Float16* __restrict__ hio,
                                                    const float* __restrict__ W,
                                                    const int* __restrict__ row_ptr,
                                                    const int* __restrict__ edge_src,
                                                    const float* __restrict__ inv_deg) {
    __shared__ __align__(16) float xs[8][128];
    const int t = threadIdx.x, w = t >> 6, l = t & 63;
    const int q = l >> 5, c = w * 32 + (l & 31);
    float wr[64];
#pragma unroll
    for (int j = 0; j < 64; j++) wr[j] = W[(64 * q + j) * 128 + c];
#pragma unroll
    for (int j = 0; j < 64; j++) asm volatile("" : "+v"(wr[j]));  // keep in VGPRs
    const u32* h2 = (const u32*)hin;  // one u32 = 2 f16 features
    const int R0 = blockIdx.x * 8;
    const int rowA = R0 + 2 * w;
    const int eA = row_ptr[rowA], eA1 = row_ptr[rowA + 1], eB1 = row_ptr[rowA + 2];
    float aAx = 0.f, aAy = 0.f, aBx = 0.f, aBy = 0.f;
    const int ecnt = eB1 - eA;
    for (int bse = 0; bse < ecnt; bse += 8) {
        u32 v[8];
#pragma unroll
        for (int i = 0; i < 8; i++) {
            int ee = eA + bse + i;
            int idx = (ee < eB1) ? ee : (eB1 - 1);  // clamp (ecnt>0 inside loop)
            v[i] = h2[(size_t)edge_src[idx] * 64 + l];
        }
#pragma unroll
        for (int i = 0; i < 8; i++) {
            int ee = eA + bse + i;
            float2 f = h2f2(v[i]);
            if (ee < eA1) { aAx += f.x; aAy += f.y; }
            else if (ee < eB1) { aBx += f.x; aBy += f.y; }
        }
    }
    const float invA = inv_deg[rowA], invB = inv_deg[rowA + 1];
    *(float2*)&xs[2 * w][2 * l] = make_float2(aAx * invA, aAy * invA);
    *(float2*)&xs[2 * w + 1][2 * l] = make_float2(aBx * invB, aBy * invB);
    __syncthreads();
#pragma unroll
    for (int r = 0; r < 8; r++) {
        float a = 0.f;
#pragma unroll
        for (int jj = 0; jj < 16; jj++) {
            float4 x4 = *(const float4*)&xs[r][64 * q + jj * 4];
            a += x4.x * wr[jj * 4] + x4.y * wr[jj * 4 + 1] +
                 x4.z * wr[jj * 4 + 2] + x4.w * wr[jj * 4 + 3];
        }
        a += __shfl_xor(a, 32);
        if (l < 32) {
            const size_t o = (size_t)(R0 + r) * 128 + c;
            hio[o] = (_Float16)fmaxf(a + (float)hio[o], 0.f);
        }
    }
}

// ---- out = h @ W_out + b_out (f32 out). 4-way K-split, cols padded 40->64 ----
__global__ __launch_bounds__(256, 4) void k_outv2(const _Float16* __restrict__ hin,
                                                  const float* __restrict__ W,
                                                  const float* __restrict__ bias,
                                                  float* __restrict__ outp) {
    __shared__ __align__(16) float xs[8][128];
    const int t = threadIdx.x, w = t >> 6, l = t & 63;
    const int q = l >> 4, c = w * 16 + (l & 15);
    const int R0 = blockIdx.x * 8;
    float wr[32];
#pragma unroll
    for (int j = 0; j < 32; j++) wr[j] = (c < 40) ? W[(32 * q + j) * 40 + c] : 0.f;
    const float b = (c < 40) ? bias[c] : 0.f;
    uint2 u = ((const uint2*)(hin + (size_t)R0 * 128))[t];
    float2 lo = h2f2(u.x), hi = h2f2(u.y);
    ((float4*)xs)[t] = make_float4(lo.x, lo.y, hi.x, hi.y);
    __syncthreads();
#pragma unroll
    for (int r = 0; r < 8; r++) {
        float a = 0.f;
#pragma unroll
        for (int jj = 0; jj < 8; jj++) {
            float4 x4 = *(const float4*)&xs[r][32 * q + jj * 4];
            a += x4.x * wr[jj * 4] + x4.y * wr[jj * 4 + 1] +
                 x4.z * wr[jj * 4 + 2] + x4.w * wr[jj * 4 + 3];
        }
        a += __shfl_xor(a, 16);
        a += __shfl_xor(a, 32);
        if (l < 16 && c < 40) outp[(size_t)(R0 + r) * 40 + c] = a + b;
    }
}

extern "C" void kernel_launch(void* const* d_in, const int* in_sizes, int n_in,
                              void* d_out, int out_size, void* d_ws, size_t ws_size,
                              hipStream_t stream) {
    // size-keyed input resolution with positional fallback (dict order)
    int ix[8] = {0, 1, 2, 3, 4, 5, 6, 7};
    int tmp[8] = {-1, -1, -1, -1, -1, -1, -1, -1};
    for (int i = 0; i < n_in && i < 8; i++) {
        switch (in_sizes[i]) {
            case 6400000: tmp[0] = i; break;
            case 1200000: case 2400000: tmp[1] = i; break;
            case 16384:   tmp[2] = i; break;
            case 128:     tmp[3] = i; break;
            case 65536:   tmp[4] = i; break;
            case 256:     tmp[5] = i; break;
            case 5120:    tmp[6] = i; break;
            case 40:      tmp[7] = i; break;
        }
    }
    int found = 0;
    for (int j = 0; j < 8; j++) found += (tmp[j] >= 0);
    if (found == 8) for (int j = 0; j < 8; j++) ix[j] = tmp[j];

    const float* X      = (const float*)d_in[ix[0]];
    const int*   adj_w  = (const int*)d_in[ix[1]];
    const float* W_in   = (const float*)d_in[ix[2]];
    const float* b_in   = (const float*)d_in[ix[3]];
    const float* W_comb = (const float*)d_in[ix[4]];
    const float* b_comb = (const float*)d_in[ix[5]];
    const float* W_out  = (const float*)d_in[ix[6]];
    const float* b_out  = (const float*)d_in[ix[7]];
    float* out = (float*)d_out;

    // ws layout: same proven offsets; h/hn now f16 (12.8MB each) -> smaller footprint
    char* base = (char*)d_ws;
    int*      deg      = (int*)(base + 0);
    int*      row_ptr  = (int*)(base + 200000);
    int*      cursor   = (int*)(base + 400004);
    float*    inv_deg  = (float*)(base + 600004);
    int*      mode     = (int*)(base + 800004);
    int*      edge_src = (int*)(base + 800008);
    _Float16* h        = (_Float16*)(base + 3200016);
    _Float16* hn       = h + 6400000;
    int*      bsum     = (int*)h;  // aliases h[0..97]; h written only after CSR build

    hipMemsetAsync(deg, 0, N_NODES * sizeof(int), stream);
    k_detect<<<1, 64, 0, stream>>>(adj_w, mode);
    k_count<<<(N_EDGES + 255) / 256, 256, 0, stream>>>(adj_w, mode, deg);
    k_scan1<<<NBLK, 1024, 0, stream>>>(deg, row_ptr, bsum);
    k_scan2<<<1, 64, 0, stream>>>(bsum);
    k_scan3<<<NBLK, 1024, 0, stream>>>(deg, row_ptr, bsum, cursor, inv_deg);
    k_fill<<<(N_EDGES + 255) / 256, 256, 0, stream>>>(adj_w, mode, cursor, edge_src);

    const float* W0t = W_comb;                  // layer 0 rows 0..127  (h part)
    const float* W0b = W_comb + 16384;          // layer 0 rows 128..255 (msg part)
    const float* W1t = W_comb + 32768;          // layer 1
    const float* W1b = W_comb + 32768 + 16384;

    k_dense<float, true><<<12500, 256, 0, stream>>>(X, h, W_in, b_in);
    k_dense<_Float16, false><<<12500, 256, 0, stream>>>(h, hn, W0t, b_comb);
    k_msggemm<<<6250, 256, 0, stream>>>(h, hn, W0b, row_ptr, edge_src, inv_deg);
    k_dense<_Float16, false><<<12500, 256, 0, stream>>>(hn, h, W1t, b_comb + 128);
    k_msggemm<<<6250, 256, 0, stream>>>(hn, h, W1b, row_ptr, edge_src, inv_deg);
    k_outv2<<<6250, 256, 0, stream>>>(h, W_out, b_out, out);
}

// Round 12
// 346.383 us; speedup vs baseline: 1.2978x; 1.2978x over previous
//
#include <hip/hip_runtime.h>
#include <hip/hip_fp16.h>

#define N_NODES 50000
#define N_EDGES 600000
#define NBLK 49  // ceil(50000/1024)

typedef unsigned int u32;
typedef unsigned short u16;
typedef _Float16 v8h __attribute__((ext_vector_type(8)));
typedef _Float16 v4h __attribute__((ext_vector_type(4)));
typedef float v4f __attribute__((ext_vector_type(4)));

__device__ __forceinline__ float2 h2f2(u32 u) {
    __half2 h = *(__half2*)&u;
    return __half22float2(h);
}

// ---------------- adj layout detection (int64 vs int32) ----------------
__global__ void k_detect(const int* __restrict__ adj_w, int* __restrict__ mode) {
    if (threadIdx.x == 0 && blockIdx.x == 0) {
        int allz = 1;
        for (int i = 1; i < 128; i += 2)
            if (adj_w[i] != 0) { allz = 0; break; }
        *mode = allz;
    }
}
__device__ __forceinline__ int adj_to(const int* a, int m, int e) {
    return m ? a[4 * e + 2] : a[2 * e + 1];
}
__device__ __forceinline__ int adj_fro(const int* a, int m, int e) {
    return m ? a[4 * e] : a[2 * e];
}

// ---------------- CSR build ----------------
__global__ void k_count(const int* __restrict__ adj_w, const int* __restrict__ mode,
                        int* __restrict__ deg) {
    int e = blockIdx.x * blockDim.x + threadIdx.x;
    if (e < N_EDGES) atomicAdd(&deg[adj_to(adj_w, *mode, e)], 1);
}

__global__ void k_scan1(const int* __restrict__ deg, int* __restrict__ row_ptr,
                        int* __restrict__ bsum) {
    __shared__ int s[1024];
    int tid = threadIdx.x, i = blockIdx.x * 1024 + tid;
    int v = (i < N_NODES) ? deg[i] : 0;
    s[tid] = v;
    __syncthreads();
    for (int off = 1; off < 1024; off <<= 1) {
        int t = (tid >= off) ? s[tid - off] : 0;
        __syncthreads();
        s[tid] += t;
        __syncthreads();
    }
    if (i < N_NODES) row_ptr[i] = s[tid] - v;
    if (tid == 1023) bsum[blockIdx.x] = s[1023];
}

__global__ void k_scan2(int* __restrict__ bsum) {
    __shared__ int s[64];
    int tid = threadIdx.x;
    int v = (tid < NBLK) ? bsum[tid] : 0;
    s[tid] = v;
    __syncthreads();
    for (int off = 1; off < 64; off <<= 1) {
        int t = (tid >= off) ? s[tid - off] : 0;
        __syncthreads();
        s[tid] += t;
        __syncthreads();
    }
    if (tid < NBLK) bsum[tid] = s[tid] - v;
}

__global__ void k_scan3(const int* __restrict__ deg, int* __restrict__ row_ptr,
                        const int* __restrict__ bsum, int* __restrict__ cursor,
                        float* __restrict__ inv_deg) {
    int i = blockIdx.x * 1024 + threadIdx.x;
    if (i < N_NODES) {
        int rp = row_ptr[i] + bsum[i >> 10];
        row_ptr[i] = rp;
        cursor[i] = rp;
        inv_deg[i] = 1.0f / fmaxf((float)deg[i], 1.0f);
    }
    if (i == 0) row_ptr[N_NODES] = N_EDGES;
}

__global__ void k_fill(const int* __restrict__ adj_w, const int* __restrict__ mode,
                       int* __restrict__ cursor, int* __restrict__ edge_src) {
    int e = blockIdx.x * blockDim.x + threadIdx.x;
    if (e < N_EDGES) {
        int m = *mode;
        int to = adj_to(adj_w, m, e);
        int slot = atomicAdd(&cursor[to], 1);
        edge_src[slot] = adj_fro(adj_w, m, e);
    }
}

// ---- weight prep: f32 row-major -> f16 transposed W^T[n][k] in ws ----
// WinT [128][128]; WcombT 2x[128][256]; WoutT [48][128] (n 40->48 zero-pad)
__global__ void k_wprep(const float* __restrict__ W_in,
                        const float* __restrict__ W_comb,
                        const float* __restrict__ W_out,
                        _Float16* __restrict__ WinT,
                        _Float16* __restrict__ WcombT,
                        _Float16* __restrict__ WoutT) {
    int idx = blockIdx.x * blockDim.x + threadIdx.x;
    if (idx < 16384) {
        int n = idx & 127, k = idx >> 7;
        WinT[n * 128 + k] = (_Float16)W_in[k * 128 + n];
    } else if (idx < 16384 + 65536) {
        int j = idx - 16384;
        int l = j >> 15, r = j & 32767;
        int n = r & 127, k = r >> 7;  // k < 256
        WcombT[l * 32768 + n * 256 + k] = (_Float16)W_comb[l * 32768 + k * 128 + n];
    } else if (idx < 16384 + 65536 + 6144) {
        int j = idx - 81920;
        int n = j >> 7, k = j & 127;
        WoutT[n * 128 + k] = (n < 40) ? (_Float16)W_out[k * 40 + n] : (_Float16)0.f;
    }
}

// ---- gather: msg[row] = (sum_{src} h[src]) * inv_deg[row]; f16 in/out ----
__global__ __launch_bounds__(256) void k_gather(const u32* __restrict__ h2,
                                                u32* __restrict__ msg2,
                                                const int* __restrict__ row_ptr,
                                                const int* __restrict__ edge_src,
                                                const float* __restrict__ inv_deg) {
    const int w = threadIdx.x >> 6, l = threadIdx.x & 63;
    const int wid = blockIdx.x * 4 + w, nw = gridDim.x * 4;
    for (int row = wid; row < N_NODES; row += nw) {
        const int e0 = row_ptr[row], e1 = row_ptr[row + 1];
        float ax = 0.f, ay = 0.f;
        for (int bse = e0; bse < e1; bse += 8) {
            u32 v[8];
#pragma unroll
            for (int i = 0; i < 8; i++) {
                int ee = bse + i;
                int idx = (ee < e1) ? ee : (e1 - 1);
                v[i] = h2[(size_t)edge_src[idx] * 64 + l];
            }
#pragma unroll
            for (int i = 0; i < 8; i++) {
                if (bse + i < e1) {
                    float2 f = h2f2(v[i]);
                    ax += f.x;
                    ay += f.y;
                }
            }
        }
        const float inv = inv_deg[row];
        __half2 o = __floats2half2_rn(ax * inv, ay * inv);
        msg2[(size_t)row * 64 + l] = *(u32*)&o;
    }
}

// ---- MFMA input GEMM: h = relu(X @ W_in + b); M-tile 32, K=128, N=128 ----
// waves: row_half = w>>1 (16 rows), col_half = w&1 (64 cols)
__global__ __launch_bounds__(256, 2) void k_in(const float* __restrict__ X,
                                               const _Float16* __restrict__ WT,
                                               const float* __restrict__ bias,
                                               _Float16* __restrict__ h) {
    __shared__ __align__(16) _Float16 xs[32][136];  // stride 136: 68dw%32=4 -> 2-way
    const int t0 = threadIdx.x, w = t0 >> 6, l = t0 & 63;
    const int R0 = blockIdx.x * 32;
    // stage X (f32 -> f16): 32 rows x 32 float4-chunks
    const float4* X4 = (const float4*)X;
#pragma unroll
    for (int i = 0; i < 4; i++) {
        int idx = i * 256 + t0;            // < 1024
        int row = idx >> 5, c4 = idx & 31;
        int rr = R0 + row;
        if (rr > N_NODES - 1) rr = N_NODES - 1;
        float4 v = X4[(size_t)rr * 32 + c4];
        v4h hv = {(_Float16)v.x, (_Float16)v.y, (_Float16)v.z, (_Float16)v.w};
        *(v4h*)&xs[row][c4 * 4] = hv;
    }
    // W-frags: n = colhalf*64 + t*16 + (l&15), k = s*32 + (l>>4)*8
    const int ch = w & 1, rh = w >> 1;
    v8h wf[4][4];
#pragma unroll
    for (int t = 0; t < 4; t++)
#pragma unroll
        for (int s = 0; s < 4; s++) {
            int n = ch * 64 + t * 16 + (l & 15);
            int k = s * 32 + (l >> 4) * 8;
            wf[t][s] = *(const v8h*)&WT[n * 128 + k];
        }
    v4f acc[4];
#pragma unroll
    for (int t = 0; t < 4; t++) acc[t] = (v4f){0.f, 0.f, 0.f, 0.f};
    __syncthreads();
#pragma unroll
    for (int s = 0; s < 4; s++) {
        v8h a = *(const v8h*)&xs[rh * 16 + (l & 15)][s * 32 + (l >> 4) * 8];
#pragma unroll
        for (int t = 0; t < 4; t++)
            acc[t] = __builtin_amdgcn_mfma_f32_16x16x32_f16(a, wf[t][s], acc[t], 0, 0, 0);
    }
#pragma unroll
    for (int t = 0; t < 4; t++) {
        int col = ch * 64 + t * 16 + (l & 15);
        float b = bias[col];
#pragma unroll
        for (int i = 0; i < 4; i++) {
            int row = R0 + rh * 16 + (l >> 4) * 4 + i;
            if (row < N_NODES)
                h[(size_t)row * 128 + col] = (_Float16)fmaxf(acc[t][i] + b, 0.f);
        }
    }
}

// ---- MFMA layer GEMM: hout = relu([h|msg] @ Wc + b); M-tile 32, K=256, N=128 ----
__global__ __launch_bounds__(256, 2) void k_layer(const _Float16* __restrict__ hin,
                                                  const _Float16* __restrict__ msg,
                                                  const _Float16* __restrict__ WT,
                                                  const float* __restrict__ bias,
                                                  _Float16* __restrict__ hout) {
    __shared__ __align__(16) _Float16 xs[32][264];  // stride 264: 132dw%32=4 -> 2-way
    const int t0 = threadIdx.x, w = t0 >> 6, l = t0 & 63;
    const int R0 = blockIdx.x * 32;
    const uint4* h4 = (const uint4*)hin;
    const uint4* m4 = (const uint4*)msg;
#pragma unroll
    for (int i = 0; i < 4; i++) {
        int idx = i * 256 + t0;             // < 1024
        int row = idx >> 5, c16 = idx & 31; // 32 16B-chunks per row (16 h + 16 msg)
        int rr = R0 + row;
        if (rr > N_NODES - 1) rr = N_NODES - 1;
        uint4 v = (c16 < 16) ? h4[(size_t)rr * 16 + c16] : m4[(size_t)rr * 16 + (c16 - 16)];
        *(uint4*)&xs[row][c16 * 8] = v;
    }
    const int ch = w & 1, rh = w >> 1;
    v8h wf[4][8];
#pragma unroll
    for (int t = 0; t < 4; t++)
#pragma unroll
        for (int s = 0; s < 8; s++) {
            int n = ch * 64 + t * 16 + (l & 15);
            int k = s * 32 + (l >> 4) * 8;
            wf[t][s] = *(const v8h*)&WT[n * 256 + k];
        }
    v4f acc[4];
#pragma unroll
    for (int t = 0; t < 4; t++) acc[t] = (v4f){0.f, 0.f, 0.f, 0.f};
    __syncthreads();
#pragma unroll
    for (int s = 0; s < 8; s++) {
        v8h a = *(const v8h*)&xs[rh * 16 + (l & 15)][s * 32 + (l >> 4) * 8];
#pragma unroll
        for (int t = 0; t < 4; t++)
            acc[t] = __builtin_amdgcn_mfma_f32_16x16x32_f16(a, wf[t][s], acc[t], 0, 0, 0);
    }
#pragma unroll
    for (int t = 0; t < 4; t++) {
        int col = ch * 64 + t * 16 + (l & 15);
        float b = bias[col];
#pragma unroll
        for (int i = 0; i < 4; i++) {
            int row = R0 + rh * 16 + (l >> 4) * 4 + i;
            if (row < N_NODES)
                hout[(size_t)row * 128 + col] = (_Float16)fmaxf(acc[t][i] + b, 0.f);
        }
    }
}

// ---- MFMA out GEMM: out = h @ W_out + b (f32); M-tile 64, K=128, N=48(40) ----
__global__ __launch_bounds__(256, 2) void k_out(const _Float16* __restrict__ hin,
                                                const _Float16* __restrict__ WT,
                                                const float* __restrict__ bias,
                                                float* __restrict__ outp) {
    __shared__ __align__(16) _Float16 xs[64][136];
    const int t0 = threadIdx.x, w = t0 >> 6, l = t0 & 63;
    const int R0 = blockIdx.x * 64;
    const uint4* h4 = (const uint4*)hin;
#pragma unroll
    for (int i = 0; i < 4; i++) {
        int idx = i * 256 + t0;             // < 1024
        int row = idx >> 4, c16 = idx & 15; // 16 16B-chunks per row
        int rr = R0 + row;
        if (rr > N_NODES - 1) rr = N_NODES - 1;
        *(uint4*)&xs[row][c16 * 8] = h4[(size_t)rr * 16 + c16];
    }
    v8h wf[3][4];
#pragma unroll
    for (int t = 0; t < 3; t++)
#pragma unroll
        for (int s = 0; s < 4; s++) {
            int n = t * 16 + (l & 15);
            int k = s * 32 + (l >> 4) * 8;
            wf[t][s] = *(const v8h*)&WT[n * 128 + k];
        }
    v4f acc[3];
#pragma unroll
    for (int t = 0; t < 3; t++) acc[t] = (v4f){0.f, 0.f, 0.f, 0.f};
    __syncthreads();
#pragma unroll
    for (int s = 0; s < 4; s++) {
        v8h a = *(const v8h*)&xs[w * 16 + (l & 15)][s * 32 + (l >> 4) * 8];
#pragma unroll
        for (int t = 0; t < 3; t++)
            acc[t] = __builtin_amdgcn_mfma_f32_16x16x32_f16(a, wf[t][s], acc[t], 0, 0, 0);
    }
#pragma unroll
    for (int t = 0; t < 3; t++) {
        int col = t * 16 + (l & 15);
        if (col < 40) {
            float b = bias[col];
#pragma unroll
            for (int i = 0; i < 4; i++) {
                int row = R0 + w * 16 + (l >> 4) * 4 + i;
                if (row < N_NODES) outp[(size_t)row * 40 + col] = acc[t][i] + b;
            }
        }
    }
}

extern "C" void kernel_launch(void* const* d_in, const int* in_sizes, int n_in,
                              void* d_out, int out_size, void* d_ws, size_t ws_size,
                              hipStream_t stream) {
    int ix[8] = {0, 1, 2, 3, 4, 5, 6, 7};
    int tmp[8] = {-1, -1, -1, -1, -1, -1, -1, -1};
    for (int i = 0; i < n_in && i < 8; i++) {
        switch (in_sizes[i]) {
            case 6400000: tmp[0] = i; break;
            case 1200000: case 2400000: tmp[1] = i; break;
            case 16384:   tmp[2] = i; break;
            case 128:     tmp[3] = i; break;
            case 65536:   tmp[4] = i; break;
            case 256:     tmp[5] = i; break;
            case 5120:    tmp[6] = i; break;
            case 40:      tmp[7] = i; break;
        }
    }
    int found = 0;
    for (int j = 0; j < 8; j++) found += (tmp[j] >= 0);
    if (found == 8) for (int j = 0; j < 8; j++) ix[j] = tmp[j];

    const float* X      = (const float*)d_in[ix[0]];
    const int*   adj_w  = (const int*)d_in[ix[1]];
    const float* W_in   = (const float*)d_in[ix[2]];
    const float* b_in   = (const float*)d_in[ix[3]];
    const float* W_comb = (const float*)d_in[ix[4]];
    const float* b_comb = (const float*)d_in[ix[5]];
    const float* W_out  = (const float*)d_in[ix[6]];
    const float* b_out  = (const float*)d_in[ix[7]];
    float* out = (float*)d_out;

    // ws layout (bytes), total ~41.8MB < proven 54.4MB
    char* base = (char*)d_ws;
    int*      deg      = (int*)(base + 0);
    int*      row_ptr  = (int*)(base + 200000);
    int*      cursor   = (int*)(base + 400004);
    float*    inv_deg  = (float*)(base + 600004);
    int*      mode     = (int*)(base + 800004);
    int*      edge_src = (int*)(base + 800008);
    _Float16* WinT     = (_Float16*)(base + 3200016);
    _Float16* WcombT   = (_Float16*)(base + 3232784);
    _Float16* WoutT    = (_Float16*)(base + 3363856);
    _Float16* hA       = (_Float16*)(base + 3376144);
    _Float16* hB       = (_Float16*)(base + 16176144);
    _Float16* msg      = (_Float16*)(base + 28976144);
    int*      bsum     = (int*)hA;  // h written only after CSR build

    hipMemsetAsync(deg, 0, N_NODES * sizeof(int), stream);
    k_detect<<<1, 64, 0, stream>>>(adj_w, mode);
    k_count<<<(N_EDGES + 255) / 256, 256, 0, stream>>>(adj_w, mode, deg);
    k_scan1<<<NBLK, 1024, 0, stream>>>(deg, row_ptr, bsum);
    k_scan2<<<1, 64, 0, stream>>>(bsum);
    k_scan3<<<NBLK, 1024, 0, stream>>>(deg, row_ptr, bsum, cursor, inv_deg);
    k_fill<<<(N_EDGES + 255) / 256, 256, 0, stream>>>(adj_w, mode, cursor, edge_src);
    k_wprep<<<344, 256, 0, stream>>>(W_in, W_comb, W_out, WinT, WcombT, WoutT);

    k_in<<<1563, 256, 0, stream>>>(X, WinT, b_in, hA);

    k_gather<<<1024, 256, 0, stream>>>((const u32*)hA, (u32*)msg, row_ptr, edge_src, inv_deg);
    k_layer<<<1563, 256, 0, stream>>>(hA, msg, WcombT, b_comb, hB);

    k_gather<<<1024, 256, 0, stream>>>((const u32*)hB, (u32*)msg, row_ptr, edge_src, inv_deg);
    k_layer<<<1563, 256, 0, stream>>>(hB, msg, WcombT + 32768, b_comb + 128, hA);

    k_out<<<782, 256, 0, stream>>>(hA, WoutT, b_out, out);
}

// Round 13
// 301.780 us; speedup vs baseline: 1.4897x; 1.1478x over previous
//
#include <hip/hip_runtime.h>
#include <hip/hip_fp16.h>

#define N_NODES 50000
#define N_EDGES 600000
#define NBLK 49  // ceil(50000/1024)

typedef unsigned int u32;
typedef _Float16 v8h __attribute__((ext_vector_type(8)));
typedef _Float16 v4h __attribute__((ext_vector_type(4)));
typedef float v4f __attribute__((ext_vector_type(4)));

__device__ __forceinline__ float2 h2f2(u32 u) {
    __half2 h = *(__half2*)&u;
    return __half22float2(h);
}

// ---------------- adj layout detection (int64 vs int32) ----------------
__global__ void k_detect(const int* __restrict__ adj_w, int* __restrict__ mode) {
    if (threadIdx.x == 0 && blockIdx.x == 0) {
        int allz = 1;
        for (int i = 1; i < 128; i += 2)
            if (adj_w[i] != 0) { allz = 0; break; }
        *mode = allz;
    }
}
__device__ __forceinline__ int adj_to(const int* a, int m, int e) {
    return m ? a[4 * e + 2] : a[2 * e + 1];
}
__device__ __forceinline__ int adj_fro(const int* a, int m, int e) {
    return m ? a[4 * e] : a[2 * e];
}

// ---------------- CSR build ----------------
__global__ void k_count(const int* __restrict__ adj_w, const int* __restrict__ mode,
                        int* __restrict__ deg) {
    int e = blockIdx.x * blockDim.x + threadIdx.x;
    if (e < N_EDGES) atomicAdd(&deg[adj_to(adj_w, *mode, e)], 1);
}

__global__ void k_scan1(const int* __restrict__ deg, int* __restrict__ row_ptr,
                        int* __restrict__ bsum) {
    __shared__ int s[1024];
    int tid = threadIdx.x, i = blockIdx.x * 1024 + tid;
    int v = (i < N_NODES) ? deg[i] : 0;
    s[tid] = v;
    __syncthreads();
    for (int off = 1; off < 1024; off <<= 1) {
        int t = (tid >= off) ? s[tid - off] : 0;
        __syncthreads();
        s[tid] += t;
        __syncthreads();
    }
    if (i < N_NODES) row_ptr[i] = s[tid] - v;
    if (tid == 1023) bsum[blockIdx.x] = s[1023];
}

__global__ void k_scan2(int* __restrict__ bsum) {
    __shared__ int s[64];
    int tid = threadIdx.x;
    int v = (tid < NBLK) ? bsum[tid] : 0;
    s[tid] = v;
    __syncthreads();
    for (int off = 1; off < 64; off <<= 1) {
        int t = (tid >= off) ? s[tid - off] : 0;
        __syncthreads();
        s[tid] += t;
        __syncthreads();
    }
    if (tid < NBLK) bsum[tid] = s[tid] - v;
}

__global__ void k_scan3(const int* __restrict__ deg, int* __restrict__ row_ptr,
                        const int* __restrict__ bsum, int* __restrict__ cursor,
                        float* __restrict__ inv_deg) {
    int i = blockIdx.x * 1024 + threadIdx.x;
    if (i < N_NODES) {
        int rp = row_ptr[i] + bsum[i >> 10];
        row_ptr[i] = rp;
        cursor[i] = rp;
        inv_deg[i] = 1.0f / fmaxf((float)deg[i], 1.0f);
    }
    if (i == 0) row_ptr[N_NODES] = N_EDGES;
}

__global__ void k_fill(const int* __restrict__ adj_w, const int* __restrict__ mode,
                       int* __restrict__ cursor, int* __restrict__ edge_src) {
    int e = blockIdx.x * blockDim.x + threadIdx.x;
    if (e < N_EDGES) {
        int m = *mode;
        int to = adj_to(adj_w, m, e);
        int slot = atomicAdd(&cursor[to], 1);
        edge_src[slot] = adj_fro(adj_w, m, e);
    }
}

// ---- weight prep: f32 row-major -> f16 transposed W^T[n][k] in ws ----
__global__ void k_wprep(const float* __restrict__ W_in,
                        const float* __restrict__ W_comb,
                        const float* __restrict__ W_out,
                        _Float16* __restrict__ WinT,
                        _Float16* __restrict__ WcombT,
                        _Float16* __restrict__ WoutT) {
    int idx = blockIdx.x * blockDim.x + threadIdx.x;
    if (idx < 16384) {
        int n = idx & 127, k = idx >> 7;
        WinT[n * 128 + k] = (_Float16)W_in[k * 128 + n];
    } else if (idx < 16384 + 65536) {
        int j = idx - 16384;
        int l = j >> 15, r = j & 32767;
        int n = r & 127, k = r >> 7;
        WcombT[l * 32768 + n * 256 + k] = (_Float16)W_comb[l * 32768 + k * 128 + n];
    } else if (idx < 16384 + 65536 + 6144) {
        int j = idx - 81920;
        int n = j >> 7, k = j & 127;
        WoutT[n * 128 + k] = (n < 40) ? (_Float16)W_out[k * 40 + n] : (_Float16)0.f;
    }
}

// ---- gather: msg[row] = (sum_{src} h[src]) * inv_deg[row]; f16 in/out ----
__global__ __launch_bounds__(256) void k_gather(const u32* __restrict__ h2,
                                                u32* __restrict__ msg2,
                                                const int* __restrict__ row_ptr,
                                                const int* __restrict__ edge_src,
                                                const float* __restrict__ inv_deg) {
    const int w = threadIdx.x >> 6, l = threadIdx.x & 63;
    const int wid = blockIdx.x * 4 + w, nw = gridDim.x * 4;
    for (int row = wid; row < N_NODES; row += nw) {
        const int e0 = row_ptr[row], e1 = row_ptr[row + 1];
        float ax = 0.f, ay = 0.f;
        for (int bse = e0; bse < e1; bse += 8) {
            u32 v[8];
#pragma unroll
            for (int i = 0; i < 8; i++) {
                int ee = bse + i;
                int idx = (ee < e1) ? ee : (e1 - 1);
                v[i] = h2[(size_t)edge_src[idx] * 64 + l];
            }
#pragma unroll
            for (int i = 0; i < 8; i++) {
                if (bse + i < e1) {
                    float2 f = h2f2(v[i]);
                    ax += f.x;
                    ay += f.y;
                }
            }
        }
        const float inv = inv_deg[row];
        __half2 o = __floats2half2_rn(ax * inv, ay * inv);
        msg2[(size_t)row * 64 + l] = *(u32*)&o;
    }
}

// ---- MFMA input GEMM: h = relu(X @ W_in + b); M-tile 32, K=128, N=128 ----
__global__ __launch_bounds__(256, 2) void k_in(const float* __restrict__ X,
                                               const _Float16* __restrict__ WT,
                                               const float* __restrict__ bias,
                                               _Float16* __restrict__ h) {
    __shared__ __align__(16) _Float16 xs[32][136];
    const int t0 = threadIdx.x, w = t0 >> 6, l = t0 & 63;
    const int R0 = blockIdx.x * 32;
    const float4* X4 = (const float4*)X;
#pragma unroll
    for (int i = 0; i < 4; i++) {
        int idx = i * 256 + t0;
        int row = idx >> 5, c4 = idx & 31;
        int rr = R0 + row;
        if (rr > N_NODES - 1) rr = N_NODES - 1;
        float4 v = X4[(size_t)rr * 32 + c4];
        v4h hv = {(_Float16)v.x, (_Float16)v.y, (_Float16)v.z, (_Float16)v.w};
        *(v4h*)&xs[row][c4 * 4] = hv;
    }
    const int ch = w & 1, rh = w >> 1;
    v8h wf[4][4];
#pragma unroll
    for (int t = 0; t < 4; t++)
#pragma unroll
        for (int s = 0; s < 4; s++) {
            int n = ch * 64 + t * 16 + (l & 15);
            int k = s * 32 + (l >> 4) * 8;
            wf[t][s] = *(const v8h*)&WT[n * 128 + k];
        }
    v4f acc[4];
#pragma unroll
    for (int t = 0; t < 4; t++) acc[t] = (v4f){0.f, 0.f, 0.f, 0.f};
    __syncthreads();
#pragma unroll
    for (int s = 0; s < 4; s++) {
        v8h a = *(const v8h*)&xs[rh * 16 + (l & 15)][s * 32 + (l >> 4) * 8];
#pragma unroll
        for (int t = 0; t < 4; t++)
            acc[t] = __builtin_amdgcn_mfma_f32_16x16x32_f16(a, wf[t][s], acc[t], 0, 0, 0);
    }
#pragma unroll
    for (int t = 0; t < 4; t++) {
        int col = ch * 64 + t * 16 + (l & 15);
        float b = bias[col];
#pragma unroll
        for (int i = 0; i < 4; i++) {
            int row = R0 + rh * 16 + (l >> 4) * 4 + i;
            if (row < N_NODES)
                h[(size_t)row * 128 + col] = (_Float16)fmaxf(acc[t][i] + b, 0.f);
        }
    }
}

// ---- MFMA layer GEMM: hout = relu([h|msg] @ Wc + b); M-tile 64, K=256, N=128 ----
// wave (rh=w>>1, ch=w&1): rows rh*32 + sub*16, cols ch*64 + t*16.
__global__ __launch_bounds__(256, 2) void k_layer(const _Float16* __restrict__ hin,
                                                  const _Float16* __restrict__ msg,
                                                  const _Float16* __restrict__ WT,
                                                  const float* __restrict__ bias,
                                                  _Float16* __restrict__ hout) {
    __shared__ __align__(16) _Float16 xs[64][264];  // 33.8KB
    const int t0 = threadIdx.x, w = t0 >> 6, l = t0 & 63;
    const int R0 = blockIdx.x * 64;
    const uint4* h4 = (const uint4*)hin;
    const uint4* m4 = (const uint4*)msg;
#pragma unroll
    for (int i = 0; i < 8; i++) {
        int idx = i * 256 + t0;             // < 2048
        int row = idx >> 5, c16 = idx & 31; // 32 16B-chunks per row (16 h + 16 msg)
        int rr = R0 + row;
        if (rr > N_NODES - 1) rr = N_NODES - 1;
        uint4 v = (c16 < 16) ? h4[(size_t)rr * 16 + c16] : m4[(size_t)rr * 16 + (c16 - 16)];
        *(uint4*)&xs[row][c16 * 8] = v;
    }
    const int ch = w & 1, rh = w >> 1;
    v8h wf[4][8];
#pragma unroll
    for (int t = 0; t < 4; t++)
#pragma unroll
        for (int s = 0; s < 8; s++) {
            int n = ch * 64 + t * 16 + (l & 15);
            int k = s * 32 + (l >> 4) * 8;
            wf[t][s] = *(const v8h*)&WT[n * 256 + k];
        }
    v4f acc[2][4];
#pragma unroll
    for (int sub = 0; sub < 2; sub++)
#pragma unroll
        for (int t = 0; t < 4; t++) acc[sub][t] = (v4f){0.f, 0.f, 0.f, 0.f};
    __syncthreads();
#pragma unroll
    for (int s = 0; s < 8; s++) {
#pragma unroll
        for (int sub = 0; sub < 2; sub++) {
            v8h a = *(const v8h*)&xs[rh * 32 + sub * 16 + (l & 15)][s * 32 + (l >> 4) * 8];
#pragma unroll
            for (int t = 0; t < 4; t++)
                acc[sub][t] = __builtin_amdgcn_mfma_f32_16x16x32_f16(a, wf[t][s], acc[sub][t], 0, 0, 0);
        }
    }
#pragma unroll
    for (int sub = 0; sub < 2; sub++)
#pragma unroll
        for (int t = 0; t < 4; t++) {
            int col = ch * 64 + t * 16 + (l & 15);
            float b = bias[col];
#pragma unroll
            for (int i = 0; i < 4; i++) {
                int row = R0 + rh * 32 + sub * 16 + (l >> 4) * 4 + i;
                if (row < N_NODES)
                    hout[(size_t)row * 128 + col] = (_Float16)fmaxf(acc[sub][t][i] + b, 0.f);
            }
        }
}

// ---- MFMA out GEMM: out = h @ W_out + b (f32); M-tile 64, K=128, N=48(40) ----
__global__ __launch_bounds__(256, 2) void k_out(const _Float16* __restrict__ hin,
                                                const _Float16* __restrict__ WT,
                                                const float* __restrict__ bias,
                                                float* __restrict__ outp) {
    __shared__ __align__(16) _Float16 xs[64][136];
    const int t0 = threadIdx.x, w = t0 >> 6, l = t0 & 63;
    const int R0 = blockIdx.x * 64;
    const uint4* h4 = (const uint4*)hin;
#pragma unroll
    for (int i = 0; i < 4; i++) {
        int idx = i * 256 + t0;
        int row = idx >> 4, c16 = idx & 15;
        int rr = R0 + row;
        if (rr > N_NODES - 1) rr = N_NODES - 1;
        *(uint4*)&xs[row][c16 * 8] = h4[(size_t)rr * 16 + c16];
    }
    v8h wf[3][4];
#pragma unroll
    for (int t = 0; t < 3; t++)
#pragma unroll
        for (int s = 0; s < 4; s++) {
            int n = t * 16 + (l & 15);
            int k = s * 32 + (l >> 4) * 8;
            wf[t][s] = *(const v8h*)&WT[n * 128 + k];
        }
    v4f acc[3];
#pragma unroll
    for (int t = 0; t < 3; t++) acc[t] = (v4f){0.f, 0.f, 0.f, 0.f};
    __syncthreads();
#pragma unroll
    for (int s = 0; s < 4; s++) {
        v8h a = *(const v8h*)&xs[w * 16 + (l & 15)][s * 32 + (l >> 4) * 8];
#pragma unroll
        for (int t = 0; t < 3; t++)
            acc[t] = __builtin_amdgcn_mfma_f32_16x16x32_f16(a, wf[t][s], acc[t], 0, 0, 0);
    }
#pragma unroll
    for (int t = 0; t < 3; t++) {
        int col = t * 16 + (l & 15);
        if (col < 40) {
            float b = bias[col];
#pragma unroll
            for (int i = 0; i < 4; i++) {
                int row = R0 + w * 16 + (l >> 4) * 4 + i;
                if (row < N_NODES) outp[(size_t)row * 40 + col] = acc[t][i] + b;
            }
        }
    }
}

extern "C" void kernel_launch(void* const* d_in, const int* in_sizes, int n_in,
                              void* d_out, int out_size, void* d_ws, size_t ws_size,
                              hipStream_t stream) {
    int ix[8] = {0, 1, 2, 3, 4, 5, 6, 7};
    int tmp[8] = {-1, -1, -1, -1, -1, -1, -1, -1};
    for (int i = 0; i < n_in && i < 8; i++) {
        switch (in_sizes[i]) {
            case 6400000: tmp[0] = i; break;
            case 1200000: case 2400000: tmp[1] = i; break;
            case 16384:   tmp[2] = i; break;
            case 128:     tmp[3] = i; break;
            case 65536:   tmp[4] = i; break;
            case 256:     tmp[5] = i; break;
            case 5120:    tmp[6] = i; break;
            case 40:      tmp[7] = i; break;
        }
    }
    int found = 0;
    for (int j = 0; j < 8; j++) found += (tmp[j] >= 0);
    if (found == 8) for (int j = 0; j < 8; j++) ix[j] = tmp[j];

    const float* X      = (const float*)d_in[ix[0]];
    const int*   adj_w  = (const int*)d_in[ix[1]];
    const float* W_in   = (const float*)d_in[ix[2]];
    const float* b_in   = (const float*)d_in[ix[3]];
    const float* W_comb = (const float*)d_in[ix[4]];
    const float* b_comb = (const float*)d_in[ix[5]];
    const float* W_out  = (const float*)d_in[ix[6]];
    const float* b_out  = (const float*)d_in[ix[7]];
    float* out = (float*)d_out;

    // ws layout (bytes), total ~41.8MB < proven 54.4MB
    char* base = (char*)d_ws;
    int*      deg      = (int*)(base + 0);
    int*      row_ptr  = (int*)(base + 200000);
    int*      cursor   = (int*)(base + 400004);
    float*    inv_deg  = (float*)(base + 600004);
    int*      mode     = (int*)(base + 800004);
    int*      edge_src = (int*)(base + 800008);
    _Float16* WinT     = (_Float16*)(base + 3200016);
    _Float16* WcombT   = (_Float16*)(base + 3232784);
    _Float16* WoutT    = (_Float16*)(base + 3363856);
    _Float16* hA       = (_Float16*)(base + 3376144);
    _Float16* hB       = (_Float16*)(base + 16176144);
    _Float16* msg      = (_Float16*)(base + 28976144);
    int*      bsum     = (int*)hA;  // h written only after CSR build

    hipMemsetAsync(deg, 0, N_NODES * sizeof(int), stream);
    k_detect<<<1, 64, 0, stream>>>(adj_w, mode);
    k_count<<<(N_EDGES + 255) / 256, 256, 0, stream>>>(adj_w, mode, deg);
    k_scan1<<<NBLK, 1024, 0, stream>>>(deg, row_ptr, bsum);
    k_scan2<<<1, 64, 0, stream>>>(bsum);
    k_scan3<<<NBLK, 1024, 0, stream>>>(deg, row_ptr, bsum, cursor, inv_deg);
    k_fill<<<(N_EDGES + 255) / 256, 256, 0, stream>>>(adj_w, mode, cursor, edge_src);
    k_wprep<<<344, 256, 0, stream>>>(W_in, W_comb, W_out, WinT, WcombT, WoutT);

    k_in<<<1563, 256, 0, stream>>>(X, WinT, b_in, hA);

    k_gather<<<2048, 256, 0, stream>>>((const u32*)hA, (u32*)msg, row_ptr, edge_src, inv_deg);
    k_layer<<<782, 256, 0, stream>>>(hA, msg, WcombT, b_comb, hB);

    k_gather<<<2048, 256, 0, stream>>>((const u32*)hB, (u32*)msg, row_ptr, edge_src, inv_deg);
    k_layer<<<782, 256, 0, stream>>>(hB, msg, WcombT + 32768, b_comb + 128, hA);

    k_out<<<782, 256, 0, stream>>>(hA, WoutT, b_out, out);
}